// Round 1
// 387.510 us; speedup vs baseline: 1.0697x; 1.0697x over previous
//
#include <hip/hip_runtime.h>
#include <cstdint>
#include <cstddef>

typedef _Float16 f16;
typedef __attribute__((ext_vector_type(8))) _Float16 half8;
typedef __attribute__((ext_vector_type(4))) _Float16 half4;
typedef __attribute__((ext_vector_type(8))) short short8;
typedef __attribute__((ext_vector_type(4))) float floatx4;
typedef __attribute__((ext_vector_type(8))) float floatx8;

__device__ __forceinline__ float rcp_(float x) { return __builtin_amdgcn_rcpf(x); }
__device__ __forceinline__ float sigm(float x) { return rcp_(1.f + __expf(-x)); }
__device__ __forceinline__ float tanh_(float x) { return 1.f - 2.f * rcp_(1.f + __expf(2.f * x)); }

// Dual-job 128x128-tile GEMM: C[M,N] = A[M,256] @ BT[N,256]^T, fp16 in/out,
// fp32 accum. Grid = tiles0 + tiles1 blocks; job0 first. Buffers padded so
// every 128-row tile is readable/writable (garbage rows OK). LDS 36 KB.
// (Now only used once, for the 32000x1024 vocab table.)
__global__ __launch_bounds__(256) void gemm128d(
    const f16* __restrict__ A0, const f16* __restrict__ B0, f16* __restrict__ C0,
    int ldc0, int nt0, int tiles0,
    const f16* __restrict__ A1, const f16* __restrict__ B1, f16* __restrict__ C1,
    int ldc1, int nt1)
{
  const f16* A; const f16* BT; f16* C; int ldc_, mi, ni;
  int bid = blockIdx.x;
  if (bid < tiles0) { A = A0; BT = B0; C = C0; ldc_ = ldc0; mi = bid / nt0; ni = bid % nt0; }
  else { int r = bid - tiles0; A = A1; BT = B1; C = C1; ldc_ = ldc1; mi = r / nt1; ni = r % nt1; }
  const int m0 = mi * 128;
  const int n0 = ni * 128;

  __shared__ short lA[128 * 72];
  __shared__ short lB[128 * 72];
  const int t = threadIdx.x;
  const int wave = t >> 6;
  const int lane = t & 63;
  const int ln = lane & 15;
  const int quad = lane >> 4;
  const int wr = wave >> 1;
  const int wc = wave & 1;

  floatx4 acc[4][4];
#pragma unroll
  for (int i = 0; i < 4; ++i)
#pragma unroll
    for (int j = 0; j < 4; ++j) acc[i][j] = (floatx4){0.f, 0.f, 0.f, 0.f};

#pragma unroll
  for (int st = 0; st < 4; ++st) {    // K = 256 in 4 stages of 64
    const int k0 = st * 64;
#pragma unroll
    for (int i = 0; i < 4; ++i) {     // 128 rows x 8 chunks of 8 halves
      int chunk = t + 256 * i;
      int row = chunk >> 3;
      int cc = chunk & 7;
      *(short8*)&lA[row * 72 + cc * 8] =
          *(const short8*)(A + (size_t)(m0 + row) * 256 + k0 + cc * 8);
      *(short8*)&lB[row * 72 + cc * 8] =
          *(const short8*)(BT + (size_t)(n0 + row) * 256 + k0 + cc * 8);
    }
    __syncthreads();
#pragma unroll
    for (int ks = 0; ks < 2; ++ks) {
      const int kk = ks * 32 + quad * 8;
      half8 a[4], b[4];
#pragma unroll
      for (int rf = 0; rf < 4; ++rf)
        a[rf] = __builtin_bit_cast(half8,
            *(const short8*)&lA[(wr * 64 + rf * 16 + ln) * 72 + kk]);
#pragma unroll
      for (int cf = 0; cf < 4; ++cf)
        b[cf] = __builtin_bit_cast(half8,
            *(const short8*)&lB[(wc * 64 + cf * 16 + ln) * 72 + kk]);
#pragma unroll
      for (int rf = 0; rf < 4; ++rf)
#pragma unroll
        for (int cf = 0; cf < 4; ++cf)
          acc[rf][cf] = __builtin_amdgcn_mfma_f32_16x16x32_f16(
              a[rf], b[cf], acc[rf][cf], 0, 0, 0);
    }
    __syncthreads();
  }
#pragma unroll
  for (int rf = 0; rf < 4; ++rf)
#pragma unroll
    for (int cf = 0; cf < 4; ++cf)
#pragma unroll
      for (int r = 0; r < 4; ++r) {
        int row = m0 + wr * 64 + rf * 16 + quad * 4 + r;
        int col = n0 + wc * 64 + cf * 16 + ln;
        C[(size_t)row * ldc_ + col] = (f16)acc[rf][cf][r];
      }
}

// fp32 inputs -> fp16 working copies (emb vectorized 4-wide; weights transposed)
__global__ __launch_bounds__(256) void prep(
    const float* __restrict__ emb, const float* __restrict__ Wioux,
    const float* __restrict__ Wfx, const float* __restrict__ Wiouh,
    const float* __restrict__ Wfh,
    f16* __restrict__ emb_h, f16* __restrict__ BTX,
    f16* __restrict__ WiouhT, f16* __restrict__ WfhT)
{
  int idx = blockIdx.x * 256 + threadIdx.x;   // 10049 blocks = 2,572,544
  if (idx < 2048000) {                        // emb: 4 elems/thread
    floatx4 v = *(const floatx4*)(emb + 4 * (size_t)idx);
    half4 o;
#pragma unroll
    for (int j = 0; j < 4; ++j) o[j] = (f16)v[j];
    *(half4*)(emb_h + 4 * (size_t)idx) = o;
  } else if (idx < 2310144) {
    int r = idx - 2048000;                    // BTX[1024,256]: Wioux^T | Wfx^T
    int j = r >> 8, k = r & 255;
    BTX[r] = (f16)((j < 768) ? Wioux[(size_t)k * 768 + j]
                             : Wfx[(size_t)k * 256 + (j - 768)]);
  } else if (idx < 2506752) {
    int r = idx - 2310144;                    // WiouhT[768,256]
    int j = r >> 8, k = r & 255;
    WiouhT[r] = (f16)Wiouh[(size_t)k * 768 + j];
  } else {
    int r = idx - 2506752;                    // WfhT[256,256]
    int j = r >> 8, k = r & 255;
    WfhT[r] = (f16)Wfh[(size_t)k * 256 + j];
  }
}

// Leaf elementwise (unchanged): block = 8 nodes; gates -> c16/h/h16; parent
// hsum16 via LDS. Only called with leaf=1 now.
__global__ __launch_bounds__(256) void elem8(
    const int* __restrict__ tokens, const f16* __restrict__ TIOUF,
    const f16* __restrict__ IOUH, const f16* __restrict__ FH,
    const float* __restrict__ bioux, const float* __restrict__ biouh,
    const float* __restrict__ bfx, const float* __restrict__ bfh,
    f16* __restrict__ c16, float* __restrict__ h, f16* __restrict__ h16,
    f16* __restrict__ hsum16, int s, int sz, int s_up, int sz_up, int leaf)
{
  __shared__ float hsh[8 * 260];
  const int t = threadIdx.x;
  const int nloc = t >> 5;
  const int d0 = (t & 31) * 8;
  const int base = s + 8 * blockIdx.x;
  const int node = base + nloc;
  const int lim = s + sz;

  if (node < lim) {
    const f16* ti = TIOUF + (size_t)tokens[node] * 1024;
    half8 t0 = *(const half8*)(ti + d0);
    half8 t1 = *(const half8*)(ti + 256 + d0);
    half8 t2 = *(const half8*)(ti + 512 + d0);
    floatx8 bi0 = *(const floatx8*)(bioux + d0) + *(const floatx8*)(biouh + d0);
    floatx8 bi1 = *(const floatx8*)(bioux + 256 + d0) + *(const floatx8*)(biouh + 256 + d0);
    floatx8 bi2 = *(const floatx8*)(bioux + 512 + d0) + *(const floatx8*)(biouh + 512 + d0);

    float cv[8];
    if (leaf) {
#pragma unroll
      for (int j = 0; j < 8; ++j)
        cv[j] = sigm((float)t0[j] + bi0[j]) * tanh_((float)t2[j] + bi2[j]);
    } else {
      const f16* io = IOUH + (size_t)(node - s) * 768;
      half8 io0 = *(const half8*)(io + d0);
      half8 io1 = *(const half8*)(io + 256 + d0);
      half8 io2 = *(const half8*)(io + 512 + d0);
      half8 t3 = *(const half8*)(ti + 768 + d0);
      floatx8 bff = *(const floatx8*)(bfx + d0) + *(const floatx8*)(bfh + d0);
      size_t ch = 4 * (size_t)node + 1;
      half8 fh0 = *(const half8*)(FH + (ch + 0) * 256 + d0);
      half8 fh1 = *(const half8*)(FH + (ch + 1) * 256 + d0);
      half8 fh2 = *(const half8*)(FH + (ch + 2) * 256 + d0);
      half8 fh3 = *(const half8*)(FH + (ch + 3) * 256 + d0);
      half8 cc0 = *(const half8*)(c16 + (ch + 0) * 256 + d0);
      half8 cc1 = *(const half8*)(c16 + (ch + 1) * 256 + d0);
      half8 cc2 = *(const half8*)(c16 + (ch + 2) * 256 + d0);
      half8 cc3 = *(const half8*)(c16 + (ch + 3) * 256 + d0);
#pragma unroll
      for (int j = 0; j < 8; ++j) {
        float xff = (float)t3[j] + bff[j];
        float v = sigm((float)t0[j] + (float)io0[j] + bi0[j]) *
                  tanh_((float)t2[j] + (float)io2[j] + bi2[j]);
        v += sigm((float)fh0[j] + xff) * (float)cc0[j];
        v += sigm((float)fh1[j] + xff) * (float)cc1[j];
        v += sigm((float)fh2[j] + xff) * (float)cc2[j];
        v += sigm((float)fh3[j] + xff) * (float)cc3[j];
        cv[j] = v;
      }
      t1 = __builtin_bit_cast(half8,
           __builtin_bit_cast(short8, t1));
#pragma unroll
      for (int j = 0; j < 8; ++j) bi1[j] += (float)io1[j];
    }

    half8 c8, h8;
    floatx8 hf;
#pragma unroll
    for (int j = 0; j < 8; ++j) {
      float hv = sigm((float)t1[j] + bi1[j]) * tanh_(cv[j]);
      c8[j] = (f16)cv[j];
      h8[j] = (f16)hv;
      hf[j] = hv;
    }
    *(half8*)(c16 + (size_t)node * 256 + d0) = c8;
    *(floatx8*)(h + (size_t)node * 256 + d0) = hf;
    *(half8*)(h16 + (size_t)node * 256 + d0) = h8;
    *(floatx8*)&hsh[nloc * 260 + d0] = hf;
  }
  __syncthreads();

  if (s_up >= 0 && t < 64) {
    int p = t >> 5;
    int dd = (t & 31) * 8;
    int parent = ((base - 1) >> 2) + p;
    if (parent < s_up + sz_up) {
      floatx8 v = *(const floatx8*)&hsh[(4 * p + 0) * 260 + dd] +
                  *(const floatx8*)&hsh[(4 * p + 1) * 260 + dd] +
                  *(const floatx8*)&hsh[(4 * p + 2) * 260 + dd] +
                  *(const floatx8*)&hsh[(4 * p + 3) * 260 + dd];
      half8 o;
#pragma unroll
      for (int j = 0; j < 8; ++j) o[j] = (f16)v[j];
      *(half8*)(hsum16 + (size_t)(parent - s_up) * 256 + dd) = o;
    }
  }
}

// Fully-fused internal level: one kernel replaces {dual GEMM + elem8}.
// Block-pair per 16-parent tile (blockIdx bit0 = which 128-dim half).
// 512 threads = 8 waves; wave = one 16-dim panel. Per wave:
//   IOUH tiles: 3 MFMA chains (i/o/u cols dim, 256+dim, 512+dim), A = hsum_in
//   FH tiles:   4 MFMA chains (child row-tiles),               A = h16[children]
// A (16 hsum rows + 64 child rows = 40 KB) staged in LDS @ stride 264
// (264*2B = 132 words; 132 % 32 = 4 -> only 2-way bank aliasing, free).
// Weights streamed from L2 (512 KB, XCD-resident). FH/IOUH stay in fp32
// accumulators -> no f16 round-trip, no HBM traffic.
// MFMA C layout (from gemm128d): row-in-tile = 4*quad + reg, col = lane&15.
//   -> IOUH lane regs = 4 SIBLING parents  => next-level hsum is in-lane sum.
//   -> FH tile rt, lane regs = the 4 children of parent (4*rt+quad)
//      => f*cc sum is in-lane; tiny per-wave 16x16 LDS bounce re-layouts fsum.
__global__ __launch_bounds__(512) void fused_level(
    const int* __restrict__ tokens, const f16* __restrict__ TIOUF,
    const f16* __restrict__ WiouhT, const f16* __restrict__ WfhT,
    const float* __restrict__ bioux, const float* __restrict__ biouh,
    const float* __restrict__ bfx, const float* __restrict__ bfh,
    f16* __restrict__ c16, float* __restrict__ h, f16* __restrict__ h16,
    const f16* __restrict__ hsum_in, f16* __restrict__ hsum_out,
    int s, int sz, int sz_up)
{
  __shared__ short lA[80 * 264];     // rows 0-15: hsum(parents); 16-79: children h16
  __shared__ float lFS[8][16][17];   // per-wave fsum transpose bounce
  __shared__ int ltok[16];

  const int t = threadIdx.x;
  const int pt = blockIdx.x >> 1;    // parent tile
  const int pg = blockIdx.x & 1;     // dim half
  const int p0 = s + pt * 16;        // first parent of tile
  const int c0 = 4 * p0 + 1;         // first child node (contiguous 64 rows)

  if (t < 16) ltok[t] = tokens[p0 + t];
#pragma unroll
  for (int i = 0; i < 5; ++i) {      // stage A: 80 rows x 256 halves
    int chunk = t + 512 * i;
    int row = chunk >> 5;
    int cc = chunk & 31;
    const f16* src = (row < 16)
        ? hsum_in + (size_t)(pt * 16 + row) * 256 + cc * 8
        : h16 + (size_t)(c0 + row - 16) * 256 + cc * 8;
    *(short8*)&lA[row * 264 + cc * 8] = *(const short8*)src;
  }
  __syncthreads();

  const int wave = t >> 6;
  const int lane = t & 63;
  const int ln = lane & 15;
  const int q = lane >> 4;
  const int dim = (pg * 8 + wave) * 16 + ln;   // 0..255

  floatx4 accI[3], accF[4];
#pragma unroll
  for (int i = 0; i < 3; ++i) accI[i] = (floatx4){0.f, 0.f, 0.f, 0.f};
#pragma unroll
  for (int i = 0; i < 4; ++i) accF[i] = (floatx4){0.f, 0.f, 0.f, 0.f};

  const short* aH = &lA[ln * 264 + 8 * q];
  const short* aC = &lA[(16 + ln) * 264 + 8 * q];
  const f16* b0p = WiouhT + (size_t)dim * 256 + 8 * q;
  const f16* b1p = WiouhT + (size_t)(256 + dim) * 256 + 8 * q;
  const f16* b2p = WiouhT + (size_t)(512 + dim) * 256 + 8 * q;
  const f16* bfp = WfhT + (size_t)dim * 256 + 8 * q;

#pragma unroll
  for (int ks = 0; ks < 8; ++ks) {   // K = 256 in 8 steps of 32
    const int ko = 32 * ks;
    half8 ah = __builtin_bit_cast(half8, *(const short8*)(aH + ko));
    half8 b0 = *(const half8*)(b0p + ko);
    half8 b1 = *(const half8*)(b1p + ko);
    half8 b2 = *(const half8*)(b2p + ko);
    half8 bf = *(const half8*)(bfp + ko);
    accI[0] = __builtin_amdgcn_mfma_f32_16x16x32_f16(ah, b0, accI[0], 0, 0, 0);
    accI[1] = __builtin_amdgcn_mfma_f32_16x16x32_f16(ah, b1, accI[1], 0, 0, 0);
    accI[2] = __builtin_amdgcn_mfma_f32_16x16x32_f16(ah, b2, accI[2], 0, 0, 0);
#pragma unroll
    for (int rt = 0; rt < 4; ++rt) {
      half8 ac = __builtin_bit_cast(half8,
          *(const short8*)(aC + rt * (16 * 264) + ko));
      accF[rt] = __builtin_amdgcn_mfma_f32_16x16x32_f16(ac, bf, accF[rt], 0, 0, 0);
    }
  }

  const float bi0 = bioux[dim] + biouh[dim];
  const float bi1 = bioux[256 + dim] + biouh[256 + dim];
  const float bi2 = bioux[512 + dim] + biouh[512 + dim];
  const float bff = bfx[dim] + bfh[dim];

  // f-gates in FH layout: tile rt, reg r -> child c0+16rt+4q+r of parent 4rt+q
#pragma unroll
  for (int rt = 0; rt < 4; ++rt) {
    int po = 4 * rt + q;
    float xff = (float)TIOUF[(size_t)ltok[po] * 1024 + 768 + dim] + bff;
    float fs = 0.f;
#pragma unroll
    for (int r = 0; r < 4; ++r) {
      size_t child = (size_t)(c0 + 16 * rt + 4 * q + r);
      fs += sigm(accF[rt][r] + xff) * (float)c16[child * 256 + dim];
    }
    lFS[wave][po][ln] = fs;
  }
  __syncthreads();   // wave-local fence (write->read same wave buffer)

  const int szrem = sz - pt * 16;
  float hsum = 0.f;
#pragma unroll
  for (int r = 0; r < 4; ++r) {      // IOUH layout: reg r -> parent 4q+r
    int po = 4 * q + r;
    const f16* tp = TIOUF + (size_t)ltok[po] * 1024;
    float iv = sigm(accI[0][r] + (float)tp[dim] + bi0);
    float ov = sigm(accI[1][r] + (float)tp[256 + dim] + bi1);
    float uv = tanh_(accI[2][r] + (float)tp[512 + dim] + bi2);
    float cn = iv * uv + lFS[wave][po][ln];
    float hn = ov * tanh_(cn);
    hsum += hn;                      // 4 regs = 4 siblings => in-lane hsum
    if (po < szrem) {                // guard tail tiles (stores only)
      size_t pi = (size_t)(p0 + po);
      c16[pi * 256 + dim] = (f16)cn;
      h16[pi * 256 + dim] = (f16)hn;
      h[pi * 256 + dim] = hn;
    }
  }
  if (hsum_out) {
    int g_row = 4 * pt + q;          // next-level relative parent row
    if (g_row < sz_up)
      hsum_out[(size_t)g_row * 256 + dim] = (f16)hsum;
  }
}

extern "C" void kernel_launch(void* const* d_in, const int* in_sizes, int n_in,
                              void* d_out, int out_size, void* d_ws, size_t ws_size,
                              hipStream_t stream) {
  const int*   tokens = (const int*)d_in[0];
  const float* emb    = (const float*)d_in[2];
  const float* Wioux  = (const float*)d_in[3];
  const float* bioux  = (const float*)d_in[4];
  const float* Wiouh  = (const float*)d_in[5];
  const float* biouh  = (const float*)d_in[6];
  const float* Wfx    = (const float*)d_in[7];
  const float* bfx    = (const float*)d_in[8];
  const float* Wfh    = (const float*)d_in[9];
  const float* bfh    = (const float*)d_in[10];
  float* h = (float*)d_out;   // fp32 h master = output [87381,256]
  (void)in_sizes; (void)n_in; (void)out_size; (void)ws_size;

  // workspace: all f16 (same layout as before; FH slot now dead, IOUH slot
  // reused as second hsum buffer for ping-pong across levels)
  f16* emb_h   = (f16*)d_ws;                        //  8,192,000
  f16* BTX     = emb_h   + 8192000;                 //    262,144
  f16* WiouhT  = BTX     + 262144;                  //    196,608
  f16* WfhT    = WiouhT  + 196608;                  //     65,536
  f16* TIOUF   = WfhT    + 65536;                   // 32,768,000 (32000x1024)
  f16* hsumB   = TIOUF   + (size_t)32768000;        // (old IOUH slot, >=16384x256)
  f16* FH_dead = hsumB   + (size_t)12582912;        // (unused)
  f16* h16     = FH_dead + (size_t)22396928;        // 22,396,928 (87488x256)
  f16* hsumA   = h16     + (size_t)22396928;        //  4,194,304 (16384x256)
  f16* c16     = hsumA   + (size_t)4194304;         // 22,396,928 (87488x256)

  // 0. convert inputs to fp16 working copies
  prep<<<10049, 256, 0, stream>>>(emb, Wioux, Wfx, Wiouh, Wfh,
                                  emb_h, BTX, WiouhT, WfhT);

  // 1. vocab table: TIOUF[v] = emb[v] @ [Wioux | Wfx]  (32000x1024, 250x8 tiles)
  gemm128d<<<2000, 256, 0, stream>>>(emb_h, BTX, TIOUF, 1024, 8, 2000,
                                     emb_h, BTX, TIOUF, 1024, 8);

  // levels, leaves -> root: (start, size)
  const int LV[9][2] = {{21845, 65536}, {5461, 16384}, {1365, 4096},
                        {341, 1024},    {85, 256},     {21, 64},
                        {5, 16},        {1, 4},        {0, 1}};

  // 2. leaves: gates + hsumA (parents at 5461)
  elem8<<<8192, 256, 0, stream>>>(tokens, TIOUF, nullptr, nullptr,
                                  bioux, biouh, bfx, bfh,
                                  c16, h, h16, hsumA, 21845, 65536, 5461, 16384, 1);

  // 3. per level: ONE fused kernel (dual GEMM in-register + elementwise + hsum)
  for (int i = 1; i < 9; ++i) {
    int s = LV[i][0], sz = LV[i][1];
    int sz_up = (i < 8) ? LV[i + 1][1] : 0;
    const f16* hin = (i & 1) ? hsumA : hsumB;
    f16* hout = (i < 8) ? ((i & 1) ? hsumB : hsumA) : nullptr;
    int blocks = 2 * ((sz + 15) / 16);
    fused_level<<<blocks, 512, 0, stream>>>(
        tokens, TIOUF, WiouhT, WfhT, bioux, biouh, bfx, bfh,
        c16, h, h16, hin, hout, s, sz, sz_up);
  }
}